// Round 4
// baseline (639.607 us; speedup 1.0000x reference)
//
#include <hip/hip_runtime.h>
#include <hip/hip_bf16.h>

using bf16 = __hip_bfloat16;
typedef __bf16 v8bf __attribute__((ext_vector_type(8)));
typedef float v4f __attribute__((ext_vector_type(4)));

#define H_ 1024
#define A_ 16
#define O_ 4
#define B_ 4096
#define P_ 2048
#define EPS_ 1e-5f

// async global->LDS, 16B per lane; lds pointer must be wave-uniform base.
__device__ __forceinline__ void gl_lds16(const void* g, void* l) {
    __builtin_amdgcn_global_load_lds(
        (const __attribute__((address_space(1))) void*)g,
        (__attribute__((address_space(3))) void*)l, 16, 0, 0);
}

// ---- gather selected rows of X,X1 -> XX (bf16); tail blocks do b12=b1+b2 --
__global__ __launch_bounds__(256) void gather_bias_k(const float* __restrict__ X,
                                                     const float* __restrict__ X1,
                                                     const int* __restrict__ pos,
                                                     bf16* __restrict__ XX,
                                                     const float* __restrict__ b1,
                                                     const float* __restrict__ b2,
                                                     float* __restrict__ b12) {
    if (blockIdx.x >= P_) {
        int i = (blockIdx.x - P_) * 256 + threadIdx.x;
        if (i < A_ * H_) b12[i] = b1[i] + b2[i];
        return;
    }
    int p = blockIdx.x;
    int row = pos[p];
    const float4* x  = (const float4*)(X  + (size_t)row * H_);
    const float4* x1 = (const float4*)(X1 + (size_t)row * H_);
    bf16* o = XX + (size_t)p * (2 * H_);
    int i = threadIdx.x;  // 0..255, H/4 = 256
    float4 v = x[i];
    __align__(8) bf16 t[4];
    t[0] = __float2bfloat16(v.x); t[1] = __float2bfloat16(v.y);
    t[2] = __float2bfloat16(v.z); t[3] = __float2bfloat16(v.w);
    *(uint2*)(o + i * 4) = *(const uint2*)t;
    float4 w = x1[i];
    t[0] = __float2bfloat16(w.x); t[1] = __float2bfloat16(w.y);
    t[2] = __float2bfloat16(w.z); t[3] = __float2bfloat16(w.w);
    *(uint2*)(o + H_ + i * 4) = *(const uint2*)t;
}

// ---- merged transpose+convert for W1,W2,W3 --------------------------------
__global__ __launch_bounds__(256) void transpose3_k(const float* __restrict__ W1s,
                                                    const float* __restrict__ W2s,
                                                    const float* __restrict__ W3s,
                                                    bf16* __restrict__ WT12,
                                                    bf16* __restrict__ WT3) {
    __shared__ float tile[64][65];
    const int which = blockIdx.z >> 4;
    const int a = blockIdx.z & 15;
    const float* src = (which == 0) ? W1s : (which == 1) ? W2s : W3s;
    bf16* dstBase = (which == 2) ? WT3 : WT12;
    const int dstK = (which == 2) ? H_ : 2 * H_;
    const int kOff = (which == 1) ? H_ : 0;

    const int k0 = blockIdx.x * 64;
    const int n0 = blockIdx.y * 64;
    const float* s = src + (size_t)a * H_ * H_;
    const int tc = threadIdx.x & 15;   // float4 column
    const int tr = threadIdx.x >> 4;   // 0..15
#pragma unroll
    for (int r = 0; r < 64; r += 16) {
        float4 v = *(const float4*)(s + (size_t)(k0 + tr + r) * H_ + n0 + tc * 4);
        tile[tr + r][tc * 4 + 0] = v.x;
        tile[tr + r][tc * 4 + 1] = v.y;
        tile[tr + r][tc * 4 + 2] = v.z;
        tile[tr + r][tc * 4 + 3] = v.w;
    }
    __syncthreads();
    bf16* d = dstBase + (size_t)a * H_ * dstK + kOff;
    const int wc = threadIdx.x & 7;   // k-chunk of 8
    const int wr = threadIdx.x >> 3;  // 0..31
#pragma unroll
    for (int r = 0; r < 64; r += 32) {
        const int n = wr + r;
        __align__(16) bf16 tmp[8];
#pragma unroll
        for (int j = 0; j < 8; j++) tmp[j] = __float2bfloat16(tile[wc * 8 + j][n]);
        *(uint4*)(d + (size_t)(n0 + n) * dstK + k0 + wc * 8) = *(const uint4*)tmp;
    }
}

// ---- bf16 GEMM, XCD-swizzled grid + double-buffered LDS, compile-time K ---
// C[a][M][N] = A[a][M][K] @ Bt[a][N][K]^T + bias.
// Grid MUST be (M/128, 8, 16) in linear order; blocks remapped so each XCD
// keeps one B-tile L2-resident across its 16 consecutive bm-blocks.
// LDS 16B-chunk XOR swizzle: slot (r,c) holds global chunk c ^ ((r>>1)&3).
template <int K, bool RELU>
__global__ __launch_bounds__(256) void gemm_bt(const bf16* __restrict__ Amat, size_t aStrideA,
                                               const bf16* __restrict__ Bt,
                                               const float* __restrict__ bias,
                                               bf16* __restrict__ C,
                                               int M, int N) {
    constexpr int BM = 128, BN = 128, BK = 32;
    constexpr int NK = K / BK;
    __shared__ __align__(16) unsigned short As[2 * BM * BK];
    __shared__ __align__(16) unsigned short Bs[2 * BN * BK];

    // ---- XCD swizzle: linear id L -> (bm, bn, a) ----
    const int L = blockIdx.x + 16 * blockIdx.y + 128 * blockIdx.z;  // dispatch order
    const int xcd = L & 7;
    const int g = L >> 3;            // per-XCD sequence 0..255
    const int bm = g & 15;           // bm fastest within XCD
    const int bna = xcd + 8 * (g >> 4);  // 0..127; all XCDs share (bm, a) phase
    const int bn = bna & 7;
    const int a = bna >> 3;

    const bf16* Ab = Amat + (size_t)a * aStrideA;
    const bf16* Bb = Bt + (size_t)a * (size_t)N * K;
    const int tid = threadIdx.x;
    const int lane = tid & 63;
    const int wave = tid >> 6;
    const int wm = (wave & 1) * 64;  // wave 2x2 grid over 128x128 tile
    const int wn = (wave >> 1) * 64;

    v4f acc[4][4];
#pragma unroll
    for (int i = 0; i < 4; i++)
#pragma unroll
        for (int j = 0; j < 4; j++) acc[i][j] = (v4f){0.f, 0.f, 0.f, 0.f};

    // staging: lane's fixed LDS slot = row r0, chunk (tid&3); loads the
    // swizzled global chunk so slot c holds global chunk c ^ ((r0>>1)&3).
    const int r0 = tid >> 2;
    const int cs = (((tid & 3) ^ ((r0 >> 1) & 3))) * 8;
    const bf16* agBase = Ab + (size_t)(bm * BM + r0) * K + cs;
    const bf16* bgBase = Bb + (size_t)(bn * BN + r0) * K + cs;
    constexpr size_t rowSkip = (size_t)64 * K;
    const int w512 = wave * 512;

    const int lr = lane & 15;
    const int q = lane >> 4;
    const int kq = (q ^ ((lr >> 1) & 3)) * 8;  // swizzled read chunk

    // prologue: stage kt=0 into buffer 0
    gl_lds16(agBase, As + w512);
    gl_lds16(agBase + rowSkip, As + 2048 + w512);
    gl_lds16(bgBase, Bs + w512);
    gl_lds16(bgBase + rowSkip, Bs + 2048 + w512);

#pragma unroll 4
    for (int kt = 0; kt < NK; ++kt) {
        __syncthreads();  // drains vmcnt -> buf[kt&1] tiles ready
        if (kt + 1 < NK) {
            const int k0 = (kt + 1) * BK;
            unsigned short* aB = As + ((kt + 1) & 1) * 4096;
            unsigned short* bB = Bs + ((kt + 1) & 1) * 4096;
            gl_lds16(agBase + k0, aB + w512);
            gl_lds16(agBase + k0 + rowSkip, aB + 2048 + w512);
            gl_lds16(bgBase + k0, bB + w512);
            gl_lds16(bgBase + k0 + rowSkip, bB + 2048 + w512);
        }
        const unsigned short* Ar = As + (kt & 1) * 4096;
        const unsigned short* Br = Bs + (kt & 1) * 4096;
        v8bf af[4], bfr[4];
#pragma unroll
        for (int mi = 0; mi < 4; mi++)
            af[mi] = *(const v8bf*)(Ar + (wm + mi * 16 + lr) * BK + kq);
#pragma unroll
        for (int ni = 0; ni < 4; ni++)
            bfr[ni] = *(const v8bf*)(Br + (wn + ni * 16 + lr) * BK + kq);
#pragma unroll
        for (int mi = 0; mi < 4; mi++)
#pragma unroll
            for (int ni = 0; ni < 4; ni++)
                acc[mi][ni] = __builtin_amdgcn_mfma_f32_16x16x32_bf16(af[mi], bfr[ni],
                                                                      acc[mi][ni], 0, 0, 0);
    }

    // epilogue: C/D layout col=lane&15, row=(lane>>4)*4+reg
    const int lq = lane >> 4;
    bf16* Cb = C + (size_t)a * M * N;
#pragma unroll
    for (int ni = 0; ni < 4; ni++) {
        const int col = bn * BN + wn + ni * 16 + lr;
        const float bv = bias[(size_t)a * N + col];
#pragma unroll
        for (int mi = 0; mi < 4; mi++) {
            const int row0 = bm * BM + wm + mi * 16 + lq * 4;
#pragma unroll
            for (int rg = 0; rg < 4; rg++) {
                float v = acc[mi][ni][rg] + bv;
                if (RELU) v = v > 0.f ? v : 0.f;
                Cb[(size_t)(row0 + rg) * N + col] = __float2bfloat16(v);
            }
        }
    }
}

// ---- fused LayerNorm + [H]->[O] head: one wave per (a,p) row --------------
// Vectorized: each lane loads 2x16B of the h-row (8 bf16 each).
__global__ __launch_bounds__(256) void ln_head_k(const bf16* __restrict__ Hb,  // [A][P][H]
                                                 const float* __restrict__ gamma,
                                                 const float* __restrict__ beta,
                                                 const float* __restrict__ W4,  // [A][H][O]
                                                 const float* __restrict__ b4,  // [A][O]
                                                 float* __restrict__ out) {     // [P][A*O]
    int w = blockIdx.x * 4 + (threadIdx.x >> 6);
    int lane = threadIdx.x & 63;
    int a = w >> 11;    // / P_
    int p = w & (P_ - 1);
    const bf16* hrow = Hb + ((size_t)a * P_ + p) * H_;
    v8bf hv0 = *(const v8bf*)(hrow + lane * 8);
    v8bf hv1 = *(const v8bf*)(hrow + 512 + lane * 8);
    float hv[16];
    float s = 0.f, ss = 0.f;
#pragma unroll
    for (int j = 0; j < 8; j++) {
        float v = (float)hv0[j];
        hv[j] = v; s += v; ss += v * v;
    }
#pragma unroll
    for (int j = 0; j < 8; j++) {
        float v = (float)hv1[j];
        hv[8 + j] = v; s += v; ss += v * v;
    }
#pragma unroll
    for (int off = 32; off; off >>= 1) {
        s += __shfl_xor(s, off);
        ss += __shfl_xor(ss, off);
    }
    float mu = s * (1.f / H_);
    float var = ss * (1.f / H_) - mu * mu;
    float rstd = rsqrtf(var + EPS_);
    const float* g = gamma + (size_t)a * H_;
    const float* be = beta + (size_t)a * H_;
    const float4* w4 = (const float4*)(W4 + (size_t)a * H_ * O_);
    float a0 = 0.f, a1 = 0.f, a2 = 0.f, a3 = 0.f;
#pragma unroll
    for (int half = 0; half < 2; half++) {
        const int kb = half * 512 + lane * 8;
        const float4 g4a = *(const float4*)(g + kb);
        const float4 g4b = *(const float4*)(g + kb + 4);
        const float4 b4a = *(const float4*)(be + kb);
        const float4 b4b = *(const float4*)(be + kb + 4);
        const float gv[8] = {g4a.x, g4a.y, g4a.z, g4a.w, g4b.x, g4b.y, g4b.z, g4b.w};
        const float bv[8] = {b4a.x, b4a.y, b4a.z, b4a.w, b4b.x, b4b.y, b4b.z, b4b.w};
#pragma unroll
        for (int j = 0; j < 8; j++) {
            const int k = kb + j;
            float hn = (hv[half * 8 + j] - mu) * rstd * gv[j] + bv[j];
            float4 wv = w4[k];
            a0 += hn * wv.x;
            a1 += hn * wv.y;
            a2 += hn * wv.z;
            a3 += hn * wv.w;
        }
    }
#pragma unroll
    for (int off = 32; off; off >>= 1) {
        a0 += __shfl_xor(a0, off);
        a1 += __shfl_xor(a1, off);
        a2 += __shfl_xor(a2, off);
        a3 += __shfl_xor(a3, off);
    }
    if (lane < 4) {
        float v = (lane == 0 ? a0 : lane == 1 ? a1 : lane == 2 ? a2 : a3) + b4[a * O_ + lane];
        out[(size_t)p * (A_ * O_) + a * O_ + lane] = v;
    }
}

extern "C" void kernel_launch(void* const* d_in, const int* in_sizes, int n_in,
                              void* d_out, int out_size, void* d_ws, size_t ws_size,
                              hipStream_t stream) {
    const float* X     = (const float*)d_in[0];
    const float* X1    = (const float*)d_in[1];
    const float* W1    = (const float*)d_in[2];
    const float* b1    = (const float*)d_in[3];
    const float* W2    = (const float*)d_in[4];
    const float* b2    = (const float*)d_in[5];
    const float* W3    = (const float*)d_in[6];
    const float* b3    = (const float*)d_in[7];
    const float* gamma = (const float*)d_in[8];
    const float* beta  = (const float*)d_in[9];
    const float* W4    = (const float*)d_in[10];
    const float* b4    = (const float*)d_in[11];
    const int* pos     = (const int*)d_in[12];
    float* out = (float*)d_out;

    char* ws = (char*)d_ws;
    bf16* XX   = (bf16*)(ws);                          // P*2H bf16   = 8 MB
    bf16* Z    = (bf16*)(ws + ((size_t)8 << 20));      // A*P*H bf16  = 64 MB
    bf16* WT3  = (bf16*)(ws + ((size_t)72 << 20));     // A*H*H bf16  = 32 MB
    bf16* WT12 = (bf16*)(ws + ((size_t)104 << 20));    // A*H*2H bf16 = 64 MB (dead after gemm1)
    float* b12 = (float*)(ws + ((size_t)168 << 20));   // A*H fp32    = 64 KB
    bf16* Hb   = WT12;                                 // alias: written by gemm2 after WT12 is dead

    gather_bias_k<<<P_ + 64, 256, 0, stream>>>(X, X1, pos, XX, b1, b2, b12);
    dim3 tgrid(H_ / 64, H_ / 64, 3 * A_);
    transpose3_k<<<tgrid, 256, 0, stream>>>(W1, W2, W3, WT12, WT3);

    dim3 g1(P_ / 128, H_ / 128, A_);
    // z = [X|X1] @ [W1;W2]^T + (b1+b2)   (K = 2H, A-matrix shared across a)
    gemm_bt<2 * H_, false><<<g1, 256, 0, stream>>>(XX, 0, WT12, b12, Z, P_, H_);
    // h = relu(z @ W3^T + b3)            (K = H, A-matrix batched over a)
    gemm_bt<H_, true><<<g1, 256, 0, stream>>>(Z, (size_t)P_ * H_, WT3, b3, Hb, P_, H_);

    ln_head_k<<<P_ * A_ / 4, 256, 0, stream>>>(Hb, gamma, beta, W4, b4, out);
}

// Round 5
// 568.290 us; speedup vs baseline: 1.1255x; 1.1255x over previous
//
#include <hip/hip_runtime.h>
#include <hip/hip_bf16.h>

using bf16 = __hip_bfloat16;
typedef __bf16 v8bf __attribute__((ext_vector_type(8)));
typedef float v4f __attribute__((ext_vector_type(4)));

#define H_ 1024
#define A_ 16
#define O_ 4
#define B_ 4096
#define P_ 2048
#define EPS_ 1e-5f

// async global->LDS, 16B per lane; lds pointer must be wave-uniform base.
__device__ __forceinline__ void gl_lds16(const void* g, void* l) {
    __builtin_amdgcn_global_load_lds(
        (const __attribute__((address_space(1))) void*)g,
        (__attribute__((address_space(3))) void*)l, 16, 0, 0);
}

// ---- gather selected rows of X,X1 -> XX (bf16); tail blocks do b12=b1+b2 --
__global__ __launch_bounds__(256) void gather_bias_k(const float* __restrict__ X,
                                                     const float* __restrict__ X1,
                                                     const int* __restrict__ pos,
                                                     bf16* __restrict__ XX,
                                                     const float* __restrict__ b1,
                                                     const float* __restrict__ b2,
                                                     float* __restrict__ b12) {
    if (blockIdx.x >= P_) {
        int i = (blockIdx.x - P_) * 256 + threadIdx.x;
        if (i < A_ * H_) b12[i] = b1[i] + b2[i];
        return;
    }
    int p = blockIdx.x;
    int row = pos[p];
    const float4* x  = (const float4*)(X  + (size_t)row * H_);
    const float4* x1 = (const float4*)(X1 + (size_t)row * H_);
    bf16* o = XX + (size_t)p * (2 * H_);
    int i = threadIdx.x;  // 0..255, H/4 = 256
    float4 v = x[i];
    __align__(8) bf16 t[4];
    t[0] = __float2bfloat16(v.x); t[1] = __float2bfloat16(v.y);
    t[2] = __float2bfloat16(v.z); t[3] = __float2bfloat16(v.w);
    *(uint2*)(o + i * 4) = *(const uint2*)t;
    float4 w = x1[i];
    t[0] = __float2bfloat16(w.x); t[1] = __float2bfloat16(w.y);
    t[2] = __float2bfloat16(w.z); t[3] = __float2bfloat16(w.w);
    *(uint2*)(o + H_ + i * 4) = *(const uint2*)t;
}

// ---- merged transpose+convert for W1,W2,W3 --------------------------------
__global__ __launch_bounds__(256) void transpose3_k(const float* __restrict__ W1s,
                                                    const float* __restrict__ W2s,
                                                    const float* __restrict__ W3s,
                                                    bf16* __restrict__ WT12,
                                                    bf16* __restrict__ WT3) {
    __shared__ float tile[64][65];
    const int which = blockIdx.z >> 4;
    const int a = blockIdx.z & 15;
    const float* src = (which == 0) ? W1s : (which == 1) ? W2s : W3s;
    bf16* dstBase = (which == 2) ? WT3 : WT12;
    const int dstK = (which == 2) ? H_ : 2 * H_;
    const int kOff = (which == 1) ? H_ : 0;

    const int k0 = blockIdx.x * 64;
    const int n0 = blockIdx.y * 64;
    const float* s = src + (size_t)a * H_ * H_;
    const int tc = threadIdx.x & 15;   // float4 column
    const int tr = threadIdx.x >> 4;   // 0..15
#pragma unroll
    for (int r = 0; r < 64; r += 16) {
        float4 v = *(const float4*)(s + (size_t)(k0 + tr + r) * H_ + n0 + tc * 4);
        tile[tr + r][tc * 4 + 0] = v.x;
        tile[tr + r][tc * 4 + 1] = v.y;
        tile[tr + r][tc * 4 + 2] = v.z;
        tile[tr + r][tc * 4 + 3] = v.w;
    }
    __syncthreads();
    bf16* d = dstBase + (size_t)a * H_ * dstK + kOff;
    const int wc = threadIdx.x & 7;   // k-chunk of 8
    const int wr = threadIdx.x >> 3;  // 0..31
#pragma unroll
    for (int r = 0; r < 64; r += 32) {
        const int n = wr + r;
        __align__(16) bf16 tmp[8];
#pragma unroll
        for (int j = 0; j < 8; j++) tmp[j] = __float2bfloat16(tile[wc * 8 + j][n]);
        *(uint4*)(d + (size_t)(n0 + n) * dstK + k0 + wc * 8) = *(const uint4*)tmp;
    }
}

// ---- bf16 GEMM, XCD-swizzled grid + double-buffered LDS pipeline ----------
// C[a][M][N] = A[a][M][K] @ Bt[a][N][K]^T + bias.  Runtime K on purpose:
// compile-time K + unroll raised VGPR 80->104, dropped occupancy 29->22%,
// regressed 182->233 us (R4). 80 VGPR / ~3 blocks/CU is the binding resource.
// Grid MUST be (M/128, 8, 16) in linear order; blocks remapped so each XCD
// keeps one B-tile L2-resident across its 16 consecutive bm-blocks.
// LDS 16B-chunk XOR swizzle: slot (r,c) holds global chunk c ^ ((r>>1)&3).
template <bool RELU>
__global__ __launch_bounds__(256) void gemm_bt(const bf16* __restrict__ Amat, size_t aStrideA,
                                               const bf16* __restrict__ Bt,
                                               const float* __restrict__ bias,
                                               bf16* __restrict__ C,
                                               int M, int N, int K) {
    constexpr int BM = 128, BN = 128, BK = 32;
    __shared__ __align__(16) unsigned short As[2 * BM * BK];
    __shared__ __align__(16) unsigned short Bs[2 * BN * BK];

    // ---- XCD swizzle: linear id L -> (bm, bn, a) ----
    const int L = blockIdx.x + 16 * blockIdx.y + 128 * blockIdx.z;  // dispatch order
    const int xcd = L & 7;
    const int g = L >> 3;            // per-XCD sequence 0..255
    const int bm = g & 15;           // bm fastest within XCD
    const int bna = xcd + 8 * (g >> 4);  // 0..127; all XCDs share (bm, a) phase
    const int bn = bna & 7;
    const int a = bna >> 3;

    const bf16* Ab = Amat + (size_t)a * aStrideA;
    const bf16* Bb = Bt + (size_t)a * (size_t)N * K;
    const int tid = threadIdx.x;
    const int lane = tid & 63;
    const int wave = tid >> 6;
    const int wm = (wave & 1) * 64;  // wave 2x2 grid over 128x128 tile
    const int wn = (wave >> 1) * 64;

    v4f acc[4][4];
#pragma unroll
    for (int i = 0; i < 4; i++)
#pragma unroll
        for (int j = 0; j < 4; j++) acc[i][j] = (v4f){0.f, 0.f, 0.f, 0.f};

    // staging: lane's fixed LDS slot = row r0, chunk (tid&3); loads the
    // swizzled global chunk so slot c holds global chunk c ^ ((r0>>1)&3).
    const int r0 = tid >> 2;
    const int cs = (((tid & 3) ^ ((r0 >> 1) & 3))) * 8;
    const bf16* agBase = Ab + (size_t)(bm * BM + r0) * K + cs;
    const bf16* bgBase = Bb + (size_t)(bn * BN + r0) * K + cs;
    const size_t rowSkip = (size_t)64 * K;
    const int w512 = wave * 512;

    const int lr = lane & 15;
    const int q = lane >> 4;
    const int kq = (q ^ ((lr >> 1) & 3)) * 8;  // swizzled read chunk

    const int nk = K / BK;

    // prologue: stage kt=0 into buffer 0
    {
        unsigned short* aB = As;  // buf 0
        unsigned short* bB = Bs;
        gl_lds16(agBase, aB + w512);
        gl_lds16(agBase + rowSkip, aB + 2048 + w512);
        gl_lds16(bgBase, bB + w512);
        gl_lds16(bgBase + rowSkip, bB + 2048 + w512);
    }

    for (int kt = 0; kt < nk; ++kt) {
        __syncthreads();  // drains vmcnt -> buf[kt&1] tiles ready
        if (kt + 1 < nk) {
            const int k0 = (kt + 1) * BK;
            unsigned short* aB = As + ((kt + 1) & 1) * 4096;
            unsigned short* bB = Bs + ((kt + 1) & 1) * 4096;
            gl_lds16(agBase + k0, aB + w512);
            gl_lds16(agBase + k0 + rowSkip, aB + 2048 + w512);
            gl_lds16(bgBase + k0, bB + w512);
            gl_lds16(bgBase + k0 + rowSkip, bB + 2048 + w512);
        }
        const unsigned short* Ar = As + (kt & 1) * 4096;
        const unsigned short* Br = Bs + (kt & 1) * 4096;
        v8bf af[4], bfr[4];
#pragma unroll
        for (int mi = 0; mi < 4; mi++)
            af[mi] = *(const v8bf*)(Ar + (wm + mi * 16 + lr) * BK + kq);
#pragma unroll
        for (int ni = 0; ni < 4; ni++)
            bfr[ni] = *(const v8bf*)(Br + (wn + ni * 16 + lr) * BK + kq);
#pragma unroll
        for (int mi = 0; mi < 4; mi++)
#pragma unroll
            for (int ni = 0; ni < 4; ni++)
                acc[mi][ni] = __builtin_amdgcn_mfma_f32_16x16x32_bf16(af[mi], bfr[ni],
                                                                      acc[mi][ni], 0, 0, 0);
    }

    // epilogue: C/D layout col=lane&15, row=(lane>>4)*4+reg
    const int lq = lane >> 4;
    bf16* Cb = C + (size_t)a * M * N;
#pragma unroll
    for (int ni = 0; ni < 4; ni++) {
        const int col = bn * BN + wn + ni * 16 + lr;
        const float bv = bias[(size_t)a * N + col];
#pragma unroll
        for (int mi = 0; mi < 4; mi++) {
            const int row0 = bm * BM + wm + mi * 16 + lq * 4;
#pragma unroll
            for (int rg = 0; rg < 4; rg++) {
                float v = acc[mi][ni][rg] + bv;
                if (RELU) v = v > 0.f ? v : 0.f;
                Cb[(size_t)(row0 + rg) * N + col] = __float2bfloat16(v);
            }
        }
    }
}

// ---- fused LayerNorm + [H]->[O] head: one wave per (a,p) row --------------
// Vectorized: each lane loads 2x16B of the h-row (8 bf16 each).
__global__ __launch_bounds__(256) void ln_head_k(const bf16* __restrict__ Hb,  // [A][P][H]
                                                 const float* __restrict__ gamma,
                                                 const float* __restrict__ beta,
                                                 const float* __restrict__ W4,  // [A][H][O]
                                                 const float* __restrict__ b4,  // [A][O]
                                                 float* __restrict__ out) {     // [P][A*O]
    int w = blockIdx.x * 4 + (threadIdx.x >> 6);
    int lane = threadIdx.x & 63;
    int a = w >> 11;    // / P_
    int p = w & (P_ - 1);
    const bf16* hrow = Hb + ((size_t)a * P_ + p) * H_;
    v8bf hv0 = *(const v8bf*)(hrow + lane * 8);
    v8bf hv1 = *(const v8bf*)(hrow + 512 + lane * 8);
    float hv[16];
    float s = 0.f, ss = 0.f;
#pragma unroll
    for (int j = 0; j < 8; j++) {
        float v = (float)hv0[j];
        hv[j] = v; s += v; ss += v * v;
    }
#pragma unroll
    for (int j = 0; j < 8; j++) {
        float v = (float)hv1[j];
        hv[8 + j] = v; s += v; ss += v * v;
    }
#pragma unroll
    for (int off = 32; off; off >>= 1) {
        s += __shfl_xor(s, off);
        ss += __shfl_xor(ss, off);
    }
    float mu = s * (1.f / H_);
    float var = ss * (1.f / H_) - mu * mu;
    float rstd = rsqrtf(var + EPS_);
    const float* g = gamma + (size_t)a * H_;
    const float* be = beta + (size_t)a * H_;
    const float4* w4 = (const float4*)(W4 + (size_t)a * H_ * O_);
    float a0 = 0.f, a1 = 0.f, a2 = 0.f, a3 = 0.f;
#pragma unroll
    for (int half = 0; half < 2; half++) {
        const int kb = half * 512 + lane * 8;
        const float4 g4a = *(const float4*)(g + kb);
        const float4 g4b = *(const float4*)(g + kb + 4);
        const float4 b4a = *(const float4*)(be + kb);
        const float4 b4b = *(const float4*)(be + kb + 4);
        const float gv[8] = {g4a.x, g4a.y, g4a.z, g4a.w, g4b.x, g4b.y, g4b.z, g4b.w};
        const float bv[8] = {b4a.x, b4a.y, b4a.z, b4a.w, b4b.x, b4b.y, b4b.z, b4b.w};
#pragma unroll
        for (int j = 0; j < 8; j++) {
            const int k = kb + j;
            float hn = (hv[half * 8 + j] - mu) * rstd * gv[j] + bv[j];
            float4 wv = w4[k];
            a0 += hn * wv.x;
            a1 += hn * wv.y;
            a2 += hn * wv.z;
            a3 += hn * wv.w;
        }
    }
#pragma unroll
    for (int off = 32; off; off >>= 1) {
        a0 += __shfl_xor(a0, off);
        a1 += __shfl_xor(a1, off);
        a2 += __shfl_xor(a2, off);
        a3 += __shfl_xor(a3, off);
    }
    if (lane < 4) {
        float v = (lane == 0 ? a0 : lane == 1 ? a1 : lane == 2 ? a2 : a3) + b4[a * O_ + lane];
        out[(size_t)p * (A_ * O_) + a * O_ + lane] = v;
    }
}

extern "C" void kernel_launch(void* const* d_in, const int* in_sizes, int n_in,
                              void* d_out, int out_size, void* d_ws, size_t ws_size,
                              hipStream_t stream) {
    const float* X     = (const float*)d_in[0];
    const float* X1    = (const float*)d_in[1];
    const float* W1    = (const float*)d_in[2];
    const float* b1    = (const float*)d_in[3];
    const float* W2    = (const float*)d_in[4];
    const float* b2    = (const float*)d_in[5];
    const float* W3    = (const float*)d_in[6];
    const float* b3    = (const float*)d_in[7];
    const float* gamma = (const float*)d_in[8];
    const float* beta  = (const float*)d_in[9];
    const float* W4    = (const float*)d_in[10];
    const float* b4    = (const float*)d_in[11];
    const int* pos     = (const int*)d_in[12];
    float* out = (float*)d_out;

    char* ws = (char*)d_ws;
    bf16* XX   = (bf16*)(ws);                          // P*2H bf16   = 8 MB
    bf16* Z    = (bf16*)(ws + ((size_t)8 << 20));      // A*P*H bf16  = 64 MB
    bf16* WT3  = (bf16*)(ws + ((size_t)72 << 20));     // A*H*H bf16  = 32 MB
    bf16* WT12 = (bf16*)(ws + ((size_t)104 << 20));    // A*H*2H bf16 = 64 MB (dead after gemm1)
    float* b12 = (float*)(ws + ((size_t)168 << 20));   // A*H fp32    = 64 KB
    bf16* Hb   = WT12;                                 // alias: written by gemm2 after WT12 is dead

    gather_bias_k<<<P_ + 64, 256, 0, stream>>>(X, X1, pos, XX, b1, b2, b12);
    dim3 tgrid(H_ / 64, H_ / 64, 3 * A_);
    transpose3_k<<<tgrid, 256, 0, stream>>>(W1, W2, W3, WT12, WT3);

    dim3 g1(P_ / 128, H_ / 128, A_);
    // z = [X|X1] @ [W1;W2]^T + (b1+b2)   (K = 2H, A-matrix shared across a)
    gemm_bt<false><<<g1, 256, 0, stream>>>(XX, 0, WT12, b12, Z, P_, H_, 2 * H_);
    // h = relu(z @ W3^T + b3)            (K = H, A-matrix batched over a)
    gemm_bt<true><<<g1, 256, 0, stream>>>(Z, (size_t)P_ * H_, WT3, b3, Hb, P_, H_, H_);

    ln_head_k<<<P_ * A_ / 4, 256, 0, stream>>>(Hb, gamma, beta, W4, b4, out);
}

// Round 6
// 502.282 us; speedup vs baseline: 1.2734x; 1.1314x over previous
//
#include <hip/hip_runtime.h>
#include <hip/hip_bf16.h>

using bf16 = __hip_bfloat16;
typedef __bf16 v8bf __attribute__((ext_vector_type(8)));
typedef float v4f __attribute__((ext_vector_type(4)));

#define H_ 1024
#define A_ 16
#define O_ 4
#define B_ 4096
#define P_ 2048
#define EPS_ 1e-5f

// async global->LDS, 16B per lane; lds pointer must be wave-uniform base.
__device__ __forceinline__ void gl_lds16(const void* g, void* l) {
    __builtin_amdgcn_global_load_lds(
        (const __attribute__((address_space(1))) void*)g,
        (__attribute__((address_space(3))) void*)l, 16, 0, 0);
}

// ---- gather selected rows of X,X1 -> XX (bf16); tail blocks do b12=b1+b2 --
__global__ __launch_bounds__(256) void gather_bias_k(const float* __restrict__ X,
                                                     const float* __restrict__ X1,
                                                     const int* __restrict__ pos,
                                                     bf16* __restrict__ XX,
                                                     const float* __restrict__ b1,
                                                     const float* __restrict__ b2,
                                                     float* __restrict__ b12) {
    if (blockIdx.x >= P_) {
        int i = (blockIdx.x - P_) * 256 + threadIdx.x;
        if (i < A_ * H_) b12[i] = b1[i] + b2[i];
        return;
    }
    int p = blockIdx.x;
    int row = pos[p];
    const float4* x  = (const float4*)(X  + (size_t)row * H_);
    const float4* x1 = (const float4*)(X1 + (size_t)row * H_);
    bf16* o = XX + (size_t)p * (2 * H_);
    int i = threadIdx.x;  // 0..255, H/4 = 256
    float4 v = x[i];
    __align__(8) bf16 t[4];
    t[0] = __float2bfloat16(v.x); t[1] = __float2bfloat16(v.y);
    t[2] = __float2bfloat16(v.z); t[3] = __float2bfloat16(v.w);
    *(uint2*)(o + i * 4) = *(const uint2*)t;
    float4 w = x1[i];
    t[0] = __float2bfloat16(w.x); t[1] = __float2bfloat16(w.y);
    t[2] = __float2bfloat16(w.z); t[3] = __float2bfloat16(w.w);
    *(uint2*)(o + H_ + i * 4) = *(const uint2*)t;
}

// ---- transpose+convert W1,W2 -> WT12 (W3 is fused into gemm1) -------------
__global__ __launch_bounds__(256) void transpose12_k(const float* __restrict__ W1s,
                                                     const float* __restrict__ W2s,
                                                     bf16* __restrict__ WT12) {
    __shared__ float tile[64][65];
    const int which = blockIdx.z >> 4;  // 0 -> W1, 1 -> W2
    const int a = blockIdx.z & 15;
    const float* src = (which == 0) ? W1s : W2s;
    const int kOff = which * H_;

    const int k0 = blockIdx.x * 64;
    const int n0 = blockIdx.y * 64;
    const float* s = src + (size_t)a * H_ * H_;
    const int tc = threadIdx.x & 15;   // float4 column
    const int tr = threadIdx.x >> 4;   // 0..15
#pragma unroll
    for (int r = 0; r < 64; r += 16) {
        float4 v = *(const float4*)(s + (size_t)(k0 + tr + r) * H_ + n0 + tc * 4);
        tile[tr + r][tc * 4 + 0] = v.x;
        tile[tr + r][tc * 4 + 1] = v.y;
        tile[tr + r][tc * 4 + 2] = v.z;
        tile[tr + r][tc * 4 + 3] = v.w;
    }
    __syncthreads();
    bf16* d = WT12 + (size_t)a * H_ * (2 * H_) + kOff;
    const int wc = threadIdx.x & 7;   // k-chunk of 8
    const int wr = threadIdx.x >> 3;  // 0..31
#pragma unroll
    for (int r = 0; r < 64; r += 32) {
        const int n = wr + r;
        __align__(16) bf16 tmp[8];
#pragma unroll
        for (int j = 0; j < 8; j++) tmp[j] = __float2bfloat16(tile[wc * 8 + j][n]);
        *(uint4*)(d + (size_t)(n0 + n) * (2 * H_) + k0 + wc * 8) = *(const uint4*)tmp;
    }
}

// ---- bf16 GEMM, XCD-swizzled grid + double-buffered LDS pipeline ----------
// C[a][M][N] = A[a][M][K] @ Bt[a][N][K]^T + bias.  Runtime K on purpose:
// compile-time K + unroll raised VGPR 80->104, dropped occupancy 29->22%,
// regressed 182->233 us (R4). 80 VGPR / low LDS is the binding resource.
// Grid (16, 8, 16 [+32 if FUSET3]) in linear order; first 2048 blocks are the
// GEMM (XCD swizzle keeps one B-tile L2-resident per XCD across 16 bm-blocks);
// with FUSET3, blocks 2048..6143 transpose W3 -> WT3 (independent work that
// overlaps the GEMM's idle memory/VALU pipes instead of serializing).
// LDS 16B-chunk XOR swizzle: slot (r,c) holds global chunk c ^ ((r>>1)&3).
template <bool RELU, bool FUSET3>
__global__ __launch_bounds__(256) void gemm_bt(const bf16* __restrict__ Amat, size_t aStrideA,
                                               const bf16* __restrict__ Bt,
                                               const float* __restrict__ bias,
                                               bf16* __restrict__ C,
                                               int M, int N, int K,
                                               const float* __restrict__ W3s,
                                               bf16* __restrict__ WT3d) {
    __shared__ __align__(16) char smem[32768];
    unsigned short* As = (unsigned short*)smem;             // 16 KB (2 bufs)
    unsigned short* Bs = (unsigned short*)(smem + 16384);   // 16 KB (2 bufs)

    const int L = blockIdx.x + 16 * blockIdx.y + 128 * blockIdx.z;  // dispatch order

    if (FUSET3 && L >= 2048) {
        // ---- W3 transpose block: src[a][K][N] fp32 -> WT3[a][N][K] bf16 ----
        const int t = L - 2048;           // 0..4095
        const int a = t >> 8;
        const int rem = t & 255;
        const int k0 = (rem & 15) * 64;
        const int n0 = (rem >> 4) * 64;
        float(*tile)[65] = (float(*)[65])smem;  // 16.6 KB < 32 KB
        const float* s = W3s + (size_t)a * H_ * H_;
        const int tc = threadIdx.x & 15;
        const int tr = threadIdx.x >> 4;
#pragma unroll
        for (int r = 0; r < 64; r += 16) {
            float4 v = *(const float4*)(s + (size_t)(k0 + tr + r) * H_ + n0 + tc * 4);
            tile[tr + r][tc * 4 + 0] = v.x;
            tile[tr + r][tc * 4 + 1] = v.y;
            tile[tr + r][tc * 4 + 2] = v.z;
            tile[tr + r][tc * 4 + 3] = v.w;
        }
        __syncthreads();
        bf16* d = WT3d + (size_t)a * H_ * H_;
        const int wc = threadIdx.x & 7;
        const int wr = threadIdx.x >> 3;
#pragma unroll
        for (int r = 0; r < 64; r += 32) {
            const int n = wr + r;
            __align__(16) bf16 tmp[8];
#pragma unroll
            for (int j = 0; j < 8; j++) tmp[j] = __float2bfloat16(tile[wc * 8 + j][n]);
            *(uint4*)(d + (size_t)(n0 + n) * H_ + k0 + wc * 8) = *(const uint4*)tmp;
        }
        return;
    }

    // ---- XCD swizzle: linear id L -> (bm, bn, a) ----
    const int xcd = L & 7;
    const int g = L >> 3;            // per-XCD sequence 0..255
    const int bm = g & 15;           // bm fastest within XCD
    const int bna = xcd + 8 * (g >> 4);  // 0..127; all XCDs share (bm, a) phase
    const int bn = bna & 7;
    const int a = bna >> 3;

    const bf16* Ab = Amat + (size_t)a * aStrideA;
    const bf16* Bb = Bt + (size_t)a * (size_t)N * K;
    const int tid = threadIdx.x;
    const int lane = tid & 63;
    const int wave = tid >> 6;
    const int wm = (wave & 1) * 64;  // wave 2x2 grid over 128x128 tile
    const int wn = (wave >> 1) * 64;

    v4f acc[4][4];
#pragma unroll
    for (int i = 0; i < 4; i++)
#pragma unroll
        for (int j = 0; j < 4; j++) acc[i][j] = (v4f){0.f, 0.f, 0.f, 0.f};

    // staging: lane's fixed LDS slot = row r0, chunk (tid&3); loads the
    // swizzled global chunk so slot c holds global chunk c ^ ((r0>>1)&3).
    const int r0 = tid >> 2;
    const int cs = (((tid & 3) ^ ((r0 >> 1) & 3))) * 8;
    const bf16* agBase = Ab + (size_t)(bm * 128 + r0) * K + cs;
    const bf16* bgBase = Bb + (size_t)(bn * 128 + r0) * K + cs;
    const size_t rowSkip = (size_t)64 * K;
    const int w512 = wave * 512;

    const int lr = lane & 15;
    const int q = lane >> 4;
    const int kq = (q ^ ((lr >> 1) & 3)) * 8;  // swizzled read chunk

    const int nk = K / 32;

    // prologue: stage kt=0 into buffer 0
    gl_lds16(agBase, As + w512);
    gl_lds16(agBase + rowSkip, As + 2048 + w512);
    gl_lds16(bgBase, Bs + w512);
    gl_lds16(bgBase + rowSkip, Bs + 2048 + w512);

    for (int kt = 0; kt < nk; ++kt) {
        __syncthreads();  // drains vmcnt -> buf[kt&1] tiles ready
        if (kt + 1 < nk) {
            const int k0 = (kt + 1) * 32;
            unsigned short* aB = As + ((kt + 1) & 1) * 4096;
            unsigned short* bB = Bs + ((kt + 1) & 1) * 4096;
            gl_lds16(agBase + k0, aB + w512);
            gl_lds16(agBase + k0 + rowSkip, aB + 2048 + w512);
            gl_lds16(bgBase + k0, bB + w512);
            gl_lds16(bgBase + k0 + rowSkip, bB + 2048 + w512);
        }
        const unsigned short* Ar = As + (kt & 1) * 4096;
        const unsigned short* Br = Bs + (kt & 1) * 4096;
        v8bf af[4], bfr[4];
#pragma unroll
        for (int mi = 0; mi < 4; mi++)
            af[mi] = *(const v8bf*)(Ar + (wm + mi * 16 + lr) * 32 + kq);
#pragma unroll
        for (int ni = 0; ni < 4; ni++)
            bfr[ni] = *(const v8bf*)(Br + (wn + ni * 16 + lr) * 32 + kq);
#pragma unroll
        for (int mi = 0; mi < 4; mi++)
#pragma unroll
            for (int ni = 0; ni < 4; ni++)
                acc[mi][ni] = __builtin_amdgcn_mfma_f32_16x16x32_bf16(af[mi], bfr[ni],
                                                                      acc[mi][ni], 0, 0, 0);
    }

    // epilogue: C/D layout col=lane&15, row=(lane>>4)*4+reg
    const int lq = lane >> 4;
    bf16* Cb = C + (size_t)a * M * N;
#pragma unroll
    for (int ni = 0; ni < 4; ni++) {
        const int col = bn * 128 + wn + ni * 16 + lr;
        const float bv = bias[(size_t)a * N + col];
#pragma unroll
        for (int mi = 0; mi < 4; mi++) {
            const int row0 = bm * 128 + wm + mi * 16 + lq * 4;
#pragma unroll
            for (int rg = 0; rg < 4; rg++) {
                float v = acc[mi][ni][rg] + bv;
                if (RELU) v = v > 0.f ? v : 0.f;
                Cb[(size_t)(row0 + rg) * N + col] = __float2bfloat16(v);
            }
        }
    }
}

// ---- fused LayerNorm + [H]->[O] head: one wave per 4 rows of one a --------
// W4/gamma/beta fragments loaded into registers ONCE per wave, reused across
// 4 rows -> cuts per-row L2 re-reads of the 16 KB W4 slice by 4x.
__global__ __launch_bounds__(256) void ln_head_k(const bf16* __restrict__ Hb,  // [A][P][H]
                                                 const float* __restrict__ gamma,
                                                 const float* __restrict__ beta,
                                                 const float* __restrict__ W4,  // [A][H][O]
                                                 const float* __restrict__ b4,  // [A][O]
                                                 float* __restrict__ out) {     // [P][A*O]
    const int w = blockIdx.x * 4 + (threadIdx.x >> 6);  // wave id, 0..8191
    const int lane = threadIdx.x & 63;
    const int a = w >> 9;          // 512 waves per a
    const int p0 = (w & 511) * 4;  // 4 rows per wave
    const float* g = gamma + (size_t)a * H_;
    const float* be = beta + (size_t)a * H_;
    const float4* w4 = (const float4*)(W4 + (size_t)a * H_ * O_);

    float gv[16], bv[16];
    float4 wv[16];
#pragma unroll
    for (int half = 0; half < 2; half++) {
        const int kb = half * 512 + lane * 8;
        const float4 g4a = *(const float4*)(g + kb);
        const float4 g4b = *(const float4*)(g + kb + 4);
        const float4 b4a = *(const float4*)(be + kb);
        const float4 b4b = *(const float4*)(be + kb + 4);
        gv[half * 8 + 0] = g4a.x; gv[half * 8 + 1] = g4a.y;
        gv[half * 8 + 2] = g4a.z; gv[half * 8 + 3] = g4a.w;
        gv[half * 8 + 4] = g4b.x; gv[half * 8 + 5] = g4b.y;
        gv[half * 8 + 6] = g4b.z; gv[half * 8 + 7] = g4b.w;
        bv[half * 8 + 0] = b4a.x; bv[half * 8 + 1] = b4a.y;
        bv[half * 8 + 2] = b4a.z; bv[half * 8 + 3] = b4a.w;
        bv[half * 8 + 4] = b4b.x; bv[half * 8 + 5] = b4b.y;
        bv[half * 8 + 6] = b4b.z; bv[half * 8 + 7] = b4b.w;
#pragma unroll
        for (int j = 0; j < 8; j++) wv[half * 8 + j] = w4[kb + j];
    }
    const float bo = b4[a * O_ + (lane & 3)];

    for (int rr = 0; rr < 4; rr++) {
        const int p = p0 + rr;
        const bf16* hrow = Hb + ((size_t)a * P_ + p) * H_;
        v8bf h0 = *(const v8bf*)(hrow + lane * 8);
        v8bf h1 = *(const v8bf*)(hrow + 512 + lane * 8);
        float hv[16];
        float s = 0.f, ss = 0.f;
#pragma unroll
        for (int j = 0; j < 8; j++) {
            float v = (float)h0[j];
            hv[j] = v; s += v; ss += v * v;
        }
#pragma unroll
        for (int j = 0; j < 8; j++) {
            float v = (float)h1[j];
            hv[8 + j] = v; s += v; ss += v * v;
        }
#pragma unroll
        for (int off = 32; off; off >>= 1) {
            s += __shfl_xor(s, off);
            ss += __shfl_xor(ss, off);
        }
        const float mu = s * (1.f / H_);
        const float var = ss * (1.f / H_) - mu * mu;
        const float rstd = rsqrtf(var + EPS_);
        float a0 = 0.f, a1 = 0.f, a2 = 0.f, a3 = 0.f;
#pragma unroll
        for (int j = 0; j < 16; j++) {
            const float hn = (hv[j] - mu) * rstd * gv[j] + bv[j];
            a0 += hn * wv[j].x;
            a1 += hn * wv[j].y;
            a2 += hn * wv[j].z;
            a3 += hn * wv[j].w;
        }
#pragma unroll
        for (int off = 32; off; off >>= 1) {
            a0 += __shfl_xor(a0, off);
            a1 += __shfl_xor(a1, off);
            a2 += __shfl_xor(a2, off);
            a3 += __shfl_xor(a3, off);
        }
        if (lane < 4) {
            const float v = (lane == 0 ? a0 : lane == 1 ? a1 : lane == 2 ? a2 : a3) + bo;
            out[(size_t)p * (A_ * O_) + a * O_ + lane] = v;
        }
    }
}

extern "C" void kernel_launch(void* const* d_in, const int* in_sizes, int n_in,
                              void* d_out, int out_size, void* d_ws, size_t ws_size,
                              hipStream_t stream) {
    const float* X     = (const float*)d_in[0];
    const float* X1    = (const float*)d_in[1];
    const float* W1    = (const float*)d_in[2];
    const float* b1    = (const float*)d_in[3];
    const float* W2    = (const float*)d_in[4];
    const float* b2    = (const float*)d_in[5];
    const float* W3    = (const float*)d_in[6];
    const float* b3    = (const float*)d_in[7];
    const float* gamma = (const float*)d_in[8];
    const float* beta  = (const float*)d_in[9];
    const float* W4    = (const float*)d_in[10];
    const float* b4    = (const float*)d_in[11];
    const int* pos     = (const int*)d_in[12];
    float* out = (float*)d_out;

    char* ws = (char*)d_ws;
    bf16* XX   = (bf16*)(ws);                          // P*2H bf16   = 8 MB
    bf16* Z    = (bf16*)(ws + ((size_t)8 << 20));      // A*P*H bf16  = 64 MB
    bf16* WT3  = (bf16*)(ws + ((size_t)72 << 20));     // A*H*H bf16  = 32 MB
    bf16* WT12 = (bf16*)(ws + ((size_t)104 << 20));    // A*H*2H bf16 = 64 MB (dead after gemm1)
    float* b12 = (float*)(ws + ((size_t)168 << 20));   // A*H fp32    = 64 KB
    bf16* Hb   = WT12;                                 // alias: written by gemm2 after WT12 is dead

    gather_bias_k<<<P_ + 64, 256, 0, stream>>>(X, X1, pos, XX, b1, b2, b12);
    dim3 tgrid(H_ / 64, H_ / 64, 2 * A_);
    transpose12_k<<<tgrid, 256, 0, stream>>>(W1, W2, WT12);

    // gemm1 (z = [X|X1] @ [W1;W2]^T + b12, K=2H) + fused W3 transpose blocks
    dim3 g1f(16, 8, 48);
    gemm_bt<false, true><<<g1f, 256, 0, stream>>>(XX, 0, WT12, b12, Z, P_, H_, 2 * H_,
                                                  W3, WT3);
    // gemm2: h = relu(z @ W3^T + b3), K=H
    dim3 g2(16, 8, 16);
    gemm_bt<true, false><<<g2, 256, 0, stream>>>(Z, (size_t)P_ * H_, WT3, b3, Hb, P_, H_, H_,
                                                 nullptr, nullptr);

    ln_head_k<<<P_ * A_ / 16, 256, 0, stream>>>(Hb, gamma, beta, W4, b4, out);
}